// Round 7
// baseline (314.716 us; speedup 1.0000x reference)
//
#include <hip/hip_runtime.h>

#define IN_DIM 64
#define FAC_K  4
#define DIM_K  16
#define SH     5                 // rows per bucket = 32 (sort granularity == agg block)
#define EPB    16384             // edges per level-1 histogram block (M = 306K)
#define CAP    1536              // max edges per 32-row bucket in LDS (mean ~512, max ~600)

typedef _Float16 h2v __attribute__((ext_vector_type(2)));
typedef _Float16 h8v __attribute__((ext_vector_type(8)));
typedef float    f4v __attribute__((ext_vector_type(4)));

__device__ inline int   h2i(h2v v) { return __builtin_bit_cast(int, v); }
__device__ inline h2v   i2h(int v) { return __builtin_bit_cast(h2v, v); }
__device__ inline h2v   pkh(float a, float b) {
    return __builtin_bit_cast(h2v, __builtin_amdgcn_cvt_pkrtz(a, b));
}

#if __has_builtin(__builtin_amdgcn_fdot2)
__device__ inline float FDOT2(h2v a, h2v b, float c) {
    return __builtin_amdgcn_fdot2(a, b, c, false);
}
#else
__device__ inline float FDOT2(h2v a, h2v b, float c) {
    return c + (float)a.x * (float)b.x + (float)a.y * (float)b.y;
}
#endif

// Quad (4-lane) butterfly adds via DPP quad_perm — softmax K-sum without LDS.
// Quads are uniformly active here (len/valid are quad-uniform).
__device__ inline float qadd_xor1(float x) {   // quad_perm [1,0,3,2]
    int y = __builtin_amdgcn_update_dpp(0, __builtin_bit_cast(int, x), 0xB1, 0xF, 0xF, true);
    return x + __builtin_bit_cast(float, y);
}
__device__ inline float qadd_xor2(float x) {   // quad_perm [2,3,0,1]
    int y = __builtin_amdgcn_update_dpp(0, __builtin_bit_cast(int, x), 0x4E, 0xF, 0xF, true);
    return x + __builtin_bit_cast(float, y);
}
// xor-8 within a 16-lane row == row_ror:8 (ctrl 0x128). Rows (16-lane node
// groups) are either fully active or fully skipped, so DPP reads are safe.
__device__ inline int rowxor8_i(int x) {
    return __builtin_amdgcn_update_dpp(0, x, 0x128, 0xF, 0xF, true);
}

union H8U { h8v v; h2v p[4]; };

// ---------------------------------------------------------------------------
// Fused kernel: blocks [0,FB) = MFMA fac GEMM; blocks [FB,FB+NB_blk) = hist
// (bucket-major flush, as in the proven r3 pipeline).
// ---------------------------------------------------------------------------
#define TSZ 1344   // per-wave LDS floats: addr = 20*o + m + 16*(o>>4), max 1323

__global__ __launch_bounds__(256) void fac_hist_kernel(
    const float* __restrict__ emb, const float* __restrict__ W,
    const float* __restrict__ b,   _Float16* __restrict__ fac16,
    const int* __restrict__ row,   int* __restrict__ H,
    int N, int E, int FB, int NB_blk, int NBUK)
{
    __shared__ float lds_pool[4 * TSZ];   // 21.5 KB; hist aliases 12.5 KB of it
    const int tid = threadIdx.x;

    if (blockIdx.x >= FB) {
        int* hist = (int*)lds_pool;       // NBUK=3125 ints = 12.5 KB <= 21.5 KB
        const int hb   = blockIdx.x - FB;
        const int base = hb * EPB;
        for (int i = tid; i < NBUK; i += 256) hist[i] = 0;
        __syncthreads();
#pragma unroll 8
        for (int i = 0; i < EPB / 256; ++i) {
            int e = base + i * 256 + tid;
            if (e < E) atomicAdd(&hist[row[e] >> SH], 1);
        }
        __syncthreads();
        for (int i = tid; i < NBUK; i += 256)
            H[(size_t)i * NB_blk + hb] = hist[i];   // bucket-major
        return;
    }

    const int lane = tid & 63;
    const int l    = lane & 15;   // A: m (node-local); B: n (out col)
    const int q    = lane >> 4;   // quad
    float* T = lds_pool + (tid >> 6) * TSZ;

    // Build B-frags once per wave: Bf[t][s], out-tile t (outs 16t..16t+15),
    // k-step s (dims 32s..32s+31). Element j: W[t][32s+8q+j][l] + b[16t+l].
    H8U Bf[4][2];
#pragma unroll
    for (int t = 0; t < 4; ++t) {
        const float bv = b[16 * t + l];
#pragma unroll
        for (int s = 0; s < 2; ++s) {
            const float* wp = W + t * 1024 + (32 * s + 8 * q) * 16 + l;
#pragma unroll
            for (int jp = 0; jp < 4; ++jp) {
                float w0 = wp[(2 * jp)     * 16] + bv;
                float w1 = wp[(2 * jp + 1) * 16] + bv;
                Bf[t][s].p[jp] = pkh(w0, w1);
            }
        }
    }

    const int ntiles = (N + 15) >> 4;
    const int nw     = FB * 4;
    const int wid    = (blockIdx.x * 256 + tid) >> 6;

    for (int tile = wid; tile < ntiles; tile += nw) {
        const int n0 = tile << 4;
        int nm = n0 + l; if (nm >= N) nm = N - 1;   // clamp (stores guarded)

        f4v acc[4];
#pragma unroll
        for (int t = 0; t < 4; ++t) acc[t] = f4v{0.f, 0.f, 0.f, 0.f};

#pragma unroll
        for (int s = 0; s < 2; ++s) {
            const float4* ap = (const float4*)(emb + (size_t)nm * 64 + 32 * s + 8 * q);
            float4 a0 = ap[0], a1 = ap[1];
            H8U A;
            A.p[0] = pkh(a0.x, a0.y); A.p[1] = pkh(a0.z, a0.w);
            A.p[2] = pkh(a1.x, a1.y); A.p[3] = pkh(a1.z, a1.w);
#pragma unroll
            for (int t = 0; t < 4; ++t)
                acc[t] = __builtin_amdgcn_mfma_f32_16x16x32_f16(A.v, Bf[t][s].v, acc[t], 0, 0, 0);
        }

        // Epilogue: leaky + LDS transpose. acc[t][r] = node m=4q+r, out o=16t+l.
#pragma unroll
        for (int t = 0; t < 4; ++t) {
            f4v v = acc[t];
            f4v vr;
#pragma unroll
            for (int r = 0; r < 4; ++r)
                vr[r] = fmaxf(v[r], 0.f) + 0.2f * fminf(v[r], 0.f);
            const int o = 16 * t + l;
            ((f4v*)(T + 20 * o + 16 * t + 4 * q))[0] = vr;   // 16B-aligned
        }
        // Same-wave LDS read-back (no barrier needed): lane = (m=l, t=q).
        float vv[16];
        float ss = 0.f;
#pragma unroll
        for (int i = 0; i < 16; ++i) {
            float x = T[20 * (16 * q + i) + 16 * q + l];
            vv[i] = x;
            ss = fmaf(x, x, ss);
        }
        float inv = 1.0f / fmaxf(sqrtf(ss), 1e-12f);
        H8U o0, o1;
#pragma unroll
        for (int jp = 0; jp < 4; ++jp) {
            o0.p[jp] = pkh(vv[2 * jp]     * inv, vv[2 * jp + 1] * inv);
            o1.p[jp] = pkh(vv[8 + 2 * jp] * inv, vv[9 + 2 * jp] * inv);
        }
        if (n0 + l < N) {
            uint4* dst = (uint4*)(fac16 + (size_t)(n0 + l) * 64 + q * 16);
            dst[0] = __builtin_bit_cast(uint4, o0.v);
            dst[1] = __builtin_bit_cast(uint4, o1.v);
        }
    }
}

// ---------------------------------------------------------------------------
// Scans (r3-proven; M is now ~306K).
// ---------------------------------------------------------------------------
__global__ __launch_bounds__(1024) void scan1_kernel(
    const int* __restrict__ in, int* __restrict__ out,
    int* __restrict__ bsum, int M)
{
    __shared__ int wsum[16];
    const int tid  = threadIdx.x;
    const int lane = tid & 63;
    const int w    = tid >> 6;
    const int gi   = blockIdx.x * 1024 + tid;

    int sc = (gi < M) ? in[gi] : 0;
#pragma unroll
    for (int d = 1; d < 64; d <<= 1) {
        int y = __shfl_up(sc, d);
        if (lane >= d) sc += y;
    }
    if (lane == 63) wsum[w] = sc;
    __syncthreads();
    if (w == 0) {
        int v = (lane < 16) ? wsum[lane] : 0;
#pragma unroll
        for (int d = 1; d < 16; d <<= 1) {
            int y = __shfl_up(v, d);
            if (lane >= d) v += y;
        }
        if (lane < 16) wsum[lane] = v;
    }
    __syncthreads();
    if (w > 0) sc += wsum[w - 1];
    if (gi < M) out[gi + 1] = sc;
    if (tid == 1023) bsum[blockIdx.x] = sc;
    if (blockIdx.x == 0 && tid == 0) out[0] = 0;
}

__global__ __launch_bounds__(1024) void scan2_kernel(int* __restrict__ bsum, int nb)
{
    __shared__ int sm[1024];
    const int tid = threadIdx.x;
    sm[tid] = (tid < nb) ? bsum[tid] : 0;
    __syncthreads();
    for (int d = 1; d < 1024; d <<= 1) {
        int t = (tid >= d) ? sm[tid - d] : 0;
        __syncthreads();
        sm[tid] += t;
        __syncthreads();
    }
    if (tid < nb) bsum[tid] = (tid > 0) ? sm[tid - 1] : 0;  // exclusive
}

// ---------------------------------------------------------------------------
// Level-1 scatter (r3-proven). Packs (row&31)<<24 | (col<<7): col pre-scaled
// to the fac16 row BYTE offset (col*128, col < 131072 so col<<7 < 2^24).
// ---------------------------------------------------------------------------
__global__ __launch_bounds__(256) void scatter1_kernel(
    const int* __restrict__ row, const int* __restrict__ col,
    const int* __restrict__ Hscan, const int* __restrict__ bsum,
    int* __restrict__ tmp, int E, int NB_blk, int NBUK)
{
    __shared__ int cur[3200];              // NBUK = 3125 cursors
    const int tid = threadIdx.x;
    const int jb  = blockIdx.x;
    const int base = jb * EPB;
    for (int i = tid; i < NBUK; i += 256) {
        int g = i * NB_blk + jb;
        int v = Hscan[g];
        if (g >= 1) v += bsum[(g - 1) >> 10];
        cur[i] = v;
    }
    __syncthreads();
#pragma unroll 8
    for (int it = 0; it < EPB / 256; ++it) {
        int e = base + it * 256 + tid;
        if (e < E) {
            int r = row[e];
            int pos = atomicAdd(&cur[r >> SH], 1);   // LDS atomic
            tmp[pos] = ((r & 31) << 24) | (col[e] << 7);
        }
    }
}

// ---------------------------------------------------------------------------
// Fused bucket-sort + 2-pass aggregate. One block per 32-row bucket (static
// mapping). r3 body with two changes: (a) depth-4 gather pipeline (8 dwordx4
// in flight per lane — the gathers are latency-bound: 45% VALUBusy at only
// 3.6 TB/s); (b) dropped the f32[16] cached head floats (re-convert fh at
// epilogue) to pay for the extra pipeline registers without spill.
// ---------------------------------------------------------------------------
__global__ __launch_bounds__(256, 8) void agg_kernel(
    const _Float16* __restrict__ fac16, const int* __restrict__ tmp,
    const int* __restrict__ Hscan, const int* __restrict__ bsum,
    float* __restrict__ nf_out, int E, int NB_blk, int NBUK, int N)
{
    __shared__ int csr[CAP];
    __shared__ int hist[32];
    __shared__ int curx[32];
    __shared__ int offl[33];

    const int tid = threadIdx.x;
    const int b   = blockIdx.x;         // bucket = 32 rows

    const int g0 = b * NB_blk;
    const int gE = g0 + NB_blk;
    const int start = Hscan[g0] + (g0 >= 1 ? bsum[(g0 - 1) >> 10] : 0);
    const int end   = Hscan[gE] + bsum[(gE - 1) >> 10];
    const int cnt   = end - start;
    const bool fits = (cnt <= CAP);

    if (tid < 32) hist[tid] = 0;
    __syncthreads();
    if (fits) {
        for (int i = tid; i < cnt; i += 256)
            atomicAdd(&hist[tmp[start + i] >> 24], 1);
    }
    __syncthreads();
    if (tid < 32) {
        int e = hist[tid];
        int sc = e;
#pragma unroll
        for (int d = 1; d < 32; d <<= 1) {
            int y = __shfl_up(sc, d);
            if (tid >= d) sc += y;
        }
        int ex = sc - e;
        offl[tid] = ex;
        curx[tid] = ex;
        if (tid == 31) offl[32] = sc;
    }
    __syncthreads();
    if (fits) {
        for (int i = tid; i < cnt; i += 256) {
            int u = tmp[start + i];
            int pos = atomicAdd(&curx[u >> 24], 1);
            csr[pos] = u & 0xFFFFFF;   // tail-row byte offset into fac16
        }
    }
    __syncthreads();

    const int grp = tid >> 4;         // node group 0..15
    const int k   = tid & 3;          // factor
    const int q   = (tid >> 2) & 3;   // edge slot (quad)
    const char* facB = (const char*)fac16;
    const int   kb   = k * 32;        // factor byte offset

    for (int round = 0; round < 2; ++round) {
        const int lr = round * 16 + grp;       // local row 0..31
        const int n  = (b << SH) + lr;
        if (n >= N) continue;

        const _Float16* frow = fac16 + (size_t)n * 64 + k * 16;
        uint4 fa = ((const uint4*)frow)[0];
        uint4 fb = ((const uint4*)frow)[1];
        h2v fh[8] = { i2h(fa.x), i2h(fa.y), i2h(fa.z), i2h(fa.w),
                      i2h(fb.x), i2h(fb.y), i2h(fb.z), i2h(fb.w) };
        h2v hh[8];
#pragma unroll
        for (int r = 0; r < 8; ++r) hh[r] = fh[r];

        int s_l = 0, len = 0;
        if (fits) { s_l = offl[lr]; len = offl[lr + 1] - s_l; }

        float vv[16];
#pragma unroll 1
        for (int pass = 0; pass < 2; ++pass) {
            h2v acc2[8];
#pragma unroll
            for (int r = 0; r < 8; ++r) acc2[r] = h2v{(_Float16)0.f, (_Float16)0.f};

            if (fits) {
                if (len > 0) {
                    // depth-4 software pipeline: 8 dwordx4 in flight per lane
                    int e0 = (q < len)      ? q      : len - 1;
                    int e1 = (4 + q < len)  ? 4 + q  : len - 1;
                    int e2 = (8 + q < len)  ? 8 + q  : len - 1;
                    int e3 = (12 + q < len) ? 12 + q : len - 1;
                    const uint4* tp0 = (const uint4*)(facB + csr[s_l + e0] + kb);
                    const uint4* tp1 = (const uint4*)(facB + csr[s_l + e1] + kb);
                    const uint4* tp2 = (const uint4*)(facB + csr[s_l + e2] + kb);
                    const uint4* tp3 = (const uint4*)(facB + csr[s_l + e3] + kb);
                    uint4 ta0 = tp0[0], tb0 = tp0[1];
                    uint4 ta1 = tp1[0], tb1 = tp1[1];
                    uint4 ta2 = tp2[0], tb2 = tp2[1];
                    uint4 ta3 = tp3[0], tb3 = tp3[1];
                    for (int i = 0; i < len; i += 4) {
                        uint4 a = ta0, bb2 = tb0;
                        ta0 = ta1; tb0 = tb1;
                        ta1 = ta2; tb1 = tb2;
                        ta2 = ta3; tb2 = tb3;
                        const bool valid = (i + q) < len;
                        if (i + 16 < len) {
                            int en = (i + 16 + q < len) ? i + 16 + q : len - 1;
                            const uint4* tpn = (const uint4*)(facB + csr[s_l + en] + kb);
                            ta3 = tpn[0]; tb3 = tpn[1];
                        }
                        h2v t2[8] = { i2h(a.x), i2h(a.y), i2h(a.z), i2h(a.w),
                                      i2h(bb2.x), i2h(bb2.y), i2h(bb2.z), i2h(bb2.w) };
                        float p = 0.f;
#pragma unroll
                        for (int r = 0; r < 8; ++r) p = FDOT2(hh[r], t2[r], p);
                        float exv = valid ? __expf(p) : 0.f;
                        float qs = qadd_xor1(exv);     // sum over K in quad (DPP)
                        qs = qadd_xor2(qs);
                        float w = valid ? exv * __builtin_amdgcn_rcpf(qs) : 0.f;
                        _Float16 wh = (_Float16)w;
                        h2v w2; w2.x = wh; w2.y = wh;
#pragma unroll
                        for (int r = 0; r < 8; ++r) acc2[r] += w2 * t2[r];   // pk_fma
                    }
                }
            } else {
                // Fallback (bucket overflow, never expected): filter-scan tmp.
                for (int i = 0; i < cnt; ++i) {
                    int u = tmp[start + i];
                    if ((u >> 24) != lr) continue;
                    const uint4* tp = (const uint4*)(facB + (u & 0xFFFFFF) + kb);
                    uint4 a = tp[0], bb2 = tp[1];
                    h2v t2[8] = { i2h(a.x), i2h(a.y), i2h(a.z), i2h(a.w),
                                  i2h(bb2.x), i2h(bb2.y), i2h(bb2.z), i2h(bb2.w) };
                    float p = 0.f;
#pragma unroll
                    for (int r = 0; r < 8; ++r) p = FDOT2(hh[r], t2[r], p);
                    float exv = __expf(p);
                    float qs = qadd_xor1(exv);
                    qs = qadd_xor2(qs);
                    float w = (q == 0) ? exv * __builtin_amdgcn_rcpf(qs) : 0.f;
                    _Float16 wh = (_Float16)w;
                    h2v w2; w2.x = wh; w2.y = wh;
#pragma unroll
                    for (int r = 0; r < 8; ++r) acc2[r] += w2 * t2[r];
                }
            }

            // cross-quad reduce: xor4 via ds_swizzle shfl, xor8 via DPP row_ror:8
#pragma unroll
            for (int r = 0; r < 8; ++r) {
                acc2[r] += i2h(__shfl_xor(h2i(acc2[r]), 4));
                acc2[r] += i2h(rowxor8_i(h2i(acc2[r])));
            }
            float ss = 0.f;
#pragma unroll
            for (int r = 0; r < 8; ++r) {
                vv[2*r]   = (float)fh[r].x + (float)acc2[r].x;
                vv[2*r+1] = (float)fh[r].y + (float)acc2[r].y;
            }
#pragma unroll
            for (int d = 0; d < 16; ++d) ss = fmaf(vv[d], vv[d], ss);
            float inv = 1.0f / fmaxf(sqrtf(ss), 1e-12f);
#pragma unroll
            for (int d = 0; d < 16; ++d) vv[d] *= inv;
            if (pass == 0) {
#pragma unroll
                for (int r = 0; r < 8; ++r) {
                    h2v t; t.x = (_Float16)vv[2*r]; t.y = (_Float16)vv[2*r+1];
                    hh[r] = t;
                }
            }
        }

        // lane (q,k) writes dims [4q,4q+4) of factor k — static-index selects
        float4 o;
        o.x = (q==0) ? vv[0]  : (q==1) ? vv[4]  : (q==2) ? vv[8]  : vv[12];
        o.y = (q==0) ? vv[1]  : (q==1) ? vv[5]  : (q==2) ? vv[9]  : vv[13];
        o.z = (q==0) ? vv[2]  : (q==1) ? vv[6]  : (q==2) ? vv[10] : vv[14];
        o.w = (q==0) ? vv[3]  : (q==1) ? vv[7]  : (q==2) ? vv[11] : vv[15];
        ((float4*)(nf_out + (size_t)n * 64 + k * 16))[q] = o;
    }
}

// ---------------------------------------------------------------------------
extern "C" void kernel_launch(void* const* d_in, const int* in_sizes, int n_in,
                              void* d_out, int out_size, void* d_ws, size_t ws_size,
                              hipStream_t stream) {
    const float* emb = (const float*)d_in[0];
    const float* W   = (const float*)d_in[1];
    const float* b   = (const float*)d_in[2];
    const int*   row = (const int*)d_in[3];
    const int*   col = (const int*)d_in[4];

    const int N = in_sizes[0] / IN_DIM;
    const int E = in_sizes[3];

    const int NBUK   = (N + 31) >> SH;         // 32-row buckets (3125)
    const int NB_blk = (E + EPB - 1) / EPB;    // level-1 blocks (98)
    const int M      = NBUK * NB_blk;          // ~306K

    float* nf = (float*)d_out;

    // Workspace
    _Float16* fac16 = (_Float16*)d_ws;                 // N*64 halves
    int*      tmp   = (int*)(fac16 + (size_t)N * 64);  // E packed (rlow|col*128)
    int*      H     = tmp + E;                         // M
    int*      Hscan = H + M;                           // M+1
    int*      bsum  = Hscan + (M + 1);                 // up to 1024

    const int nb1 = (M + 1023) / 1024;
    const int FB  = 512;                               // fac blocks (2048 waves)

    fac_hist_kernel<<<FB + NB_blk, 256, 0, stream>>>(
        emb, W, b, fac16, row, H, N, E, FB, NB_blk, NBUK);
    scan1_kernel<<<nb1, 1024, 0, stream>>>(H, Hscan, bsum, M);
    scan2_kernel<<<1, 1024, 0, stream>>>(bsum, nb1);
    scatter1_kernel<<<NB_blk, 256, 0, stream>>>(row, col, Hscan, bsum, tmp, E, NB_blk, NBUK);
    agg_kernel<<<NBUK, 256, 0, stream>>>(fac16, tmp, Hscan, bsum, nf, E, NB_blk, NBUK, N);
}

// Round 8
// 229.662 us; speedup vs baseline: 1.3703x; 1.3703x over previous
//
#include <hip/hip_runtime.h>

#define IN_DIM 64
#define FAC_K  4
#define DIM_K  16
#define SH     5                 // rows per bucket = 32 (sort granularity == agg block)
#define EPB    8192              // edges per level-1 histogram block (196 blocks)
#define CAP    1536              // max edges per 32-row bucket in LDS (mean ~512, max ~600)

typedef _Float16 h2v __attribute__((ext_vector_type(2)));
typedef _Float16 h8v __attribute__((ext_vector_type(8)));
typedef float    f4v __attribute__((ext_vector_type(4)));

__device__ inline int   h2i(h2v v) { return __builtin_bit_cast(int, v); }
__device__ inline h2v   i2h(int v) { return __builtin_bit_cast(h2v, v); }
__device__ inline h2v   pkh(float a, float b) {
    return __builtin_bit_cast(h2v, __builtin_amdgcn_cvt_pkrtz(a, b));
}

#if __has_builtin(__builtin_amdgcn_fdot2)
__device__ inline float FDOT2(h2v a, h2v b, float c) {
    return __builtin_amdgcn_fdot2(a, b, c, false);
}
#else
__device__ inline float FDOT2(h2v a, h2v b, float c) {
    return c + (float)a.x * (float)b.x + (float)a.y * (float)b.y;
}
#endif

// Quad (4-lane) butterfly adds via DPP quad_perm — softmax K-sum without LDS.
// Quads are uniformly active here (len/valid are quad-uniform).
__device__ inline float qadd_xor1(float x) {   // quad_perm [1,0,3,2]
    int y = __builtin_amdgcn_update_dpp(0, __builtin_bit_cast(int, x), 0xB1, 0xF, 0xF, true);
    return x + __builtin_bit_cast(float, y);
}
__device__ inline float qadd_xor2(float x) {   // quad_perm [2,3,0,1]
    int y = __builtin_amdgcn_update_dpp(0, __builtin_bit_cast(int, x), 0x4E, 0xF, 0xF, true);
    return x + __builtin_bit_cast(float, y);
}
// xor-8 within a 16-lane row == row_ror:8 (ctrl 0x128). Rows (16-lane node
// groups) are either fully active or fully skipped, so DPP reads are safe.
__device__ inline int rowxor8_i(int x) {
    return __builtin_amdgcn_update_dpp(0, x, 0x128, 0xF, 0xF, true);
}

union H8U { h8v v; h2v p[4]; };

// ---------------------------------------------------------------------------
// Fused kernel: blocks [0,FB) = MFMA fac GEMM; blocks [FB,FB+NB_blk) = hist.
// Hist flush is BLOCK-major H[hb*NBUK+i] (coalesced stores — r3's bucket-major
// flush was 613K strided 4B stores = ~39 MB of write-allocate line traffic).
// Hist block 0 also zeroes the scan1 last-block ticket (stream-ordered).
// ---------------------------------------------------------------------------
#define TSZ 1344   // per-wave LDS floats: addr = 20*o + m + 16*(o>>4), max 1323

__global__ __launch_bounds__(256) void fac_hist_kernel(
    const float* __restrict__ emb, const float* __restrict__ W,
    const float* __restrict__ b,   _Float16* __restrict__ fac16,
    const int* __restrict__ row,   int* __restrict__ H,
    int* __restrict__ cnt,
    int N, int E, int FB, int NB_blk, int NBUK)
{
    __shared__ float lds_pool[4 * TSZ];   // 21.5 KB; hist aliases 12.5 KB of it
    const int tid = threadIdx.x;

    if (blockIdx.x >= FB) {
        int* hist = (int*)lds_pool;       // NBUK=3125 ints = 12.5 KB <= 21.5 KB
        const int hb   = blockIdx.x - FB;
        const int base = hb * EPB;
        if (hb == 0 && tid == 0) *cnt = 0;   // scan1 ticket reset (replay-safe)
        for (int i = tid; i < NBUK; i += 256) hist[i] = 0;
        __syncthreads();
#pragma unroll
        for (int i = 0; i < EPB / 256; ++i) {
            int e = base + i * 256 + tid;
            if (e < E) atomicAdd(&hist[row[e] >> SH], 1);
        }
        __syncthreads();
        for (int i = tid; i < NBUK; i += 256)
            H[(size_t)hb * NBUK + i] = hist[i];   // block-major, coalesced
        return;
    }

    const int lane = tid & 63;
    const int l    = lane & 15;   // A: m (node-local); B: n (out col)
    const int q    = lane >> 4;   // quad
    float* T = lds_pool + (tid >> 6) * TSZ;

    // Build B-frags once per wave: Bf[t][s], out-tile t (outs 16t..16t+15),
    // k-step s (dims 32s..32s+31). Element j: W[t][32s+8q+j][l] + b[16t+l].
    H8U Bf[4][2];
#pragma unroll
    for (int t = 0; t < 4; ++t) {
        const float bv = b[16 * t + l];
#pragma unroll
        for (int s = 0; s < 2; ++s) {
            const float* wp = W + t * 1024 + (32 * s + 8 * q) * 16 + l;
#pragma unroll
            for (int jp = 0; jp < 4; ++jp) {
                float w0 = wp[(2 * jp)     * 16] + bv;
                float w1 = wp[(2 * jp + 1) * 16] + bv;
                Bf[t][s].p[jp] = pkh(w0, w1);
            }
        }
    }

    const int ntiles = (N + 15) >> 4;
    const int nw     = FB * 4;
    const int wid    = (blockIdx.x * 256 + tid) >> 6;

    for (int tile = wid; tile < ntiles; tile += nw) {
        const int n0 = tile << 4;
        int nm = n0 + l; if (nm >= N) nm = N - 1;   // clamp (stores guarded)

        f4v acc[4];
#pragma unroll
        for (int t = 0; t < 4; ++t) acc[t] = f4v{0.f, 0.f, 0.f, 0.f};

#pragma unroll
        for (int s = 0; s < 2; ++s) {
            const float4* ap = (const float4*)(emb + (size_t)nm * 64 + 32 * s + 8 * q);
            float4 a0 = ap[0], a1 = ap[1];
            H8U A;
            A.p[0] = pkh(a0.x, a0.y); A.p[1] = pkh(a0.z, a0.w);
            A.p[2] = pkh(a1.x, a1.y); A.p[3] = pkh(a1.z, a1.w);
#pragma unroll
            for (int t = 0; t < 4; ++t)
                acc[t] = __builtin_amdgcn_mfma_f32_16x16x32_f16(A.v, Bf[t][s].v, acc[t], 0, 0, 0);
        }

        // Epilogue: leaky + LDS transpose. acc[t][r] = node m=4q+r, out o=16t+l.
#pragma unroll
        for (int t = 0; t < 4; ++t) {
            f4v v = acc[t];
            f4v vr;
#pragma unroll
            for (int r = 0; r < 4; ++r)
                vr[r] = fmaxf(v[r], 0.f) + 0.2f * fminf(v[r], 0.f);
            const int o = 16 * t + l;
            ((f4v*)(T + 20 * o + 16 * t + 4 * q))[0] = vr;   // 16B-aligned
        }
        // Same-wave LDS read-back (no barrier needed): lane = (m=l, t=q).
        float vv[16];
        float ss = 0.f;
#pragma unroll
        for (int i = 0; i < 16; ++i) {
            float x = T[20 * (16 * q + i) + 16 * q + l];
            vv[i] = x;
            ss = fmaf(x, x, ss);
        }
        float inv = 1.0f / fmaxf(sqrtf(ss), 1e-12f);
        H8U o0, o1;
#pragma unroll
        for (int jp = 0; jp < 4; ++jp) {
            o0.p[jp] = pkh(vv[2 * jp]     * inv, vv[2 * jp + 1] * inv);
            o1.p[jp] = pkh(vv[8 + 2 * jp] * inv, vv[9 + 2 * jp] * inv);
        }
        if (n0 + l < N) {
            uint4* dst = (uint4*)(fac16 + (size_t)(n0 + l) * 64 + q * 16);
            dst[0] = __builtin_bit_cast(uint4, o0.v);
            dst[1] = __builtin_bit_cast(uint4, o1.v);
        }
    }
}

// ---------------------------------------------------------------------------
// scan1: reads block-major H through the bucket-major index map (strided
// reads, L2-resident, 600-block parallelism), writes bucket-major partial
// prefix out[] (coalesced) + bsum. The LAST block to finish (device-scope
// ticket, release/acquire via threadfence) then scans bsum in LDS — the old
// scan2 kernel is folded in, removing one launch.
// ---------------------------------------------------------------------------
__global__ __launch_bounds__(1024) void scan1_kernel(
    const int* __restrict__ H, int* __restrict__ out,
    int* __restrict__ bsum, int* __restrict__ cnt,
    int M, int NB_blk, int NBUK)
{
    __shared__ int wsum[16];
    __shared__ int sm[1024];
    __shared__ int ticket;
    const int tid  = threadIdx.x;
    const int lane = tid & 63;
    const int w    = tid >> 6;
    const int gi   = blockIdx.x * 1024 + tid;

    int sc = 0;
    if (gi < M) {
        int ib = gi / NB_blk;                  // bucket
        int jb = gi - ib * NB_blk;             // hist block
        sc = H[(size_t)jb * NBUK + ib];        // transposed read
    }
#pragma unroll
    for (int d = 1; d < 64; d <<= 1) {
        int y = __shfl_up(sc, d);
        if (lane >= d) sc += y;
    }
    if (lane == 63) wsum[w] = sc;
    __syncthreads();
    if (w == 0) {
        int v = (lane < 16) ? wsum[lane] : 0;
#pragma unroll
        for (int d = 1; d < 16; d <<= 1) {
            int y = __shfl_up(v, d);
            if (lane >= d) v += y;
        }
        if (lane < 16) wsum[lane] = v;
    }
    __syncthreads();
    if (w > 0) sc += wsum[w - 1];
    if (gi < M) out[gi + 1] = sc;
    if (blockIdx.x == 0 && tid == 0) out[0] = 0;

    if (tid == 1023) {
        bsum[blockIdx.x] = sc;
        __threadfence();                       // release bsum store
        ticket = atomicAdd(cnt, 1);
    }
    __syncthreads();
    if (ticket == (int)gridDim.x - 1) {        // last block: fold scan2
        __threadfence();                       // acquire all bsum stores
        const int nb = gridDim.x;
        sm[tid] = (tid < nb) ? bsum[tid] : 0;
        __syncthreads();
        for (int d = 1; d < 1024; d <<= 1) {
            int t = (tid >= d) ? sm[tid - d] : 0;
            __syncthreads();
            sm[tid] += t;
            __syncthreads();
        }
        if (tid < nb) bsum[tid] = (tid > 0) ? sm[tid - 1] : 0;  // exclusive
    }
}

// ---------------------------------------------------------------------------
// Level-1 scatter (r3-proven). Packs (row&31)<<24 | (col<<7): col pre-scaled
// to the fac16 row BYTE offset (col*128, col < 131072 so col<<7 < 2^24).
// ---------------------------------------------------------------------------
__global__ __launch_bounds__(256) void scatter1_kernel(
    const int* __restrict__ row, const int* __restrict__ col,
    const int* __restrict__ Hscan, const int* __restrict__ bsum,
    int* __restrict__ tmp, int E, int NB_blk, int NBUK)
{
    __shared__ int cur[3200];              // NBUK = 3125 cursors
    const int tid = threadIdx.x;
    const int jb  = blockIdx.x;
    const int base = jb * EPB;
    for (int i = tid; i < NBUK; i += 256) {
        int g = i * NB_blk + jb;
        int v = Hscan[g];
        if (g >= 1) v += bsum[(g - 1) >> 10];
        cur[i] = v;
    }
    __syncthreads();
#pragma unroll
    for (int it = 0; it < EPB / 256; ++it) {
        int e = base + it * 256 + tid;
        if (e < E) {
            int r = row[e];
            int pos = atomicAdd(&cur[r >> SH], 1);   // LDS atomic
            tmp[pos] = ((r & 31) << 24) | (col[e] << 7);
        }
    }
}

// ---------------------------------------------------------------------------
// Fused bucket-sort + 2-pass aggregate. One block per 32-row bucket; depth-2
// gather pipeline — EXACT r3 body (71.3 µs proven; depth-4 spilled to
// scratch: r7 WRITE_SIZE 69->175 MB).
// ---------------------------------------------------------------------------
__global__ __launch_bounds__(256, 8) void agg_kernel(
    const _Float16* __restrict__ fac16, const int* __restrict__ tmp,
    const int* __restrict__ Hscan, const int* __restrict__ bsum,
    float* __restrict__ nf_out, int E, int NB_blk, int NBUK, int N)
{
    __shared__ int csr[CAP];
    __shared__ int hist[32];
    __shared__ int curx[32];
    __shared__ int offl[33];

    const int tid = threadIdx.x;
    const int b   = blockIdx.x;         // bucket = 32 rows

    const int g0 = b * NB_blk;
    const int gE = g0 + NB_blk;
    const int start = Hscan[g0] + (g0 >= 1 ? bsum[(g0 - 1) >> 10] : 0);
    const int end   = Hscan[gE] + bsum[(gE - 1) >> 10];
    const int cnt   = end - start;
    const bool fits = (cnt <= CAP);

    if (tid < 32) hist[tid] = 0;
    __syncthreads();
    if (fits) {
        for (int i = tid; i < cnt; i += 256)
            atomicAdd(&hist[tmp[start + i] >> 24], 1);
    }
    __syncthreads();
    if (tid < 32) {
        int e = hist[tid];
        int sc = e;
#pragma unroll
        for (int d = 1; d < 32; d <<= 1) {
            int y = __shfl_up(sc, d);
            if (tid >= d) sc += y;
        }
        int ex = sc - e;
        offl[tid] = ex;
        curx[tid] = ex;
        if (tid == 31) offl[32] = sc;
    }
    __syncthreads();
    if (fits) {
        for (int i = tid; i < cnt; i += 256) {
            int u = tmp[start + i];
            int pos = atomicAdd(&curx[u >> 24], 1);
            csr[pos] = u & 0xFFFFFF;   // tail-row byte offset into fac16
        }
    }
    __syncthreads();

    const int grp = tid >> 4;         // node group 0..15
    const int k   = tid & 3;          // factor
    const int q   = (tid >> 2) & 3;   // edge slot (quad)
    const char* facB = (const char*)fac16;
    const int   kb   = k * 32;        // factor byte offset

    for (int round = 0; round < 2; ++round) {
        const int lr = round * 16 + grp;       // local row 0..31
        const int n  = (b << SH) + lr;
        if (n >= N) continue;

        const _Float16* frow = fac16 + (size_t)n * 64 + k * 16;
        uint4 fa = ((const uint4*)frow)[0];
        uint4 fb = ((const uint4*)frow)[1];
        h2v fh[8] = { i2h(fa.x), i2h(fa.y), i2h(fa.z), i2h(fa.w),
                      i2h(fb.x), i2h(fb.y), i2h(fb.z), i2h(fb.w) };
        float f32[16];
#pragma unroll
        for (int r = 0; r < 8; ++r) { f32[2*r] = (float)fh[r].x; f32[2*r+1] = (float)fh[r].y; }
        h2v hh[8];
#pragma unroll
        for (int r = 0; r < 8; ++r) hh[r] = fh[r];

        int s_l = 0, len = 0;
        if (fits) { s_l = offl[lr]; len = offl[lr + 1] - s_l; }

        float vv[16];
#pragma unroll 1
        for (int pass = 0; pass < 2; ++pass) {
            h2v acc2[8];
#pragma unroll
            for (int r = 0; r < 8; ++r) acc2[r] = h2v{(_Float16)0.f, (_Float16)0.f};

            if (fits) {
                if (len > 0) {
                    // depth-2 software pipeline: 4 dwordx4 in flight per lane
                    int e0 = (q < len) ? q : len - 1;
                    const uint4* tp0 = (const uint4*)(facB + csr[s_l + e0] + kb);
                    uint4 ta0 = tp0[0], tb0 = tp0[1];
                    uint4 ta1 = ta0, tb1 = tb0;
                    if (len > 4) {
                        int e1 = (4 + q < len) ? 4 + q : len - 1;
                        const uint4* tp1 = (const uint4*)(facB + csr[s_l + e1] + kb);
                        ta1 = tp1[0]; tb1 = tp1[1];
                    }
                    for (int i = 0; i < len; i += 4) {
                        uint4 a = ta0, bb2 = tb0;
                        ta0 = ta1; tb0 = tb1;
                        const bool valid = (i + q) < len;
                        if (i + 8 < len) {
                            int e2 = (i + 8 + q < len) ? i + 8 + q : len - 1;
                            const uint4* tp2 = (const uint4*)(facB + csr[s_l + e2] + kb);
                            ta1 = tp2[0]; tb1 = tp2[1];
                        }
                        h2v t2[8] = { i2h(a.x), i2h(a.y), i2h(a.z), i2h(a.w),
                                      i2h(bb2.x), i2h(bb2.y), i2h(bb2.z), i2h(bb2.w) };
                        float p = 0.f;
#pragma unroll
                        for (int r = 0; r < 8; ++r) p = FDOT2(hh[r], t2[r], p);
                        float exv = valid ? __expf(p) : 0.f;
                        float qs = qadd_xor1(exv);     // sum over K in quad (DPP)
                        qs = qadd_xor2(qs);
                        float w = valid ? exv * __builtin_amdgcn_rcpf(qs) : 0.f;
                        _Float16 wh = (_Float16)w;
                        h2v w2; w2.x = wh; w2.y = wh;
#pragma unroll
                        for (int r = 0; r < 8; ++r) acc2[r] += w2 * t2[r];   // pk_fma
                    }
                }
            } else {
                // Fallback (bucket overflow, never expected): filter-scan tmp.
                for (int i = 0; i < cnt; ++i) {
                    int u = tmp[start + i];
                    if ((u >> 24) != lr) continue;
                    const uint4* tp = (const uint4*)(facB + (u & 0xFFFFFF) + kb);
                    uint4 a = tp[0], bb2 = tp[1];
                    h2v t2[8] = { i2h(a.x), i2h(a.y), i2h(a.z), i2h(a.w),
                                  i2h(bb2.x), i2h(bb2.y), i2h(bb2.z), i2h(bb2.w) };
                    float p = 0.f;
#pragma unroll
                    for (int r = 0; r < 8; ++r) p = FDOT2(hh[r], t2[r], p);
                    float exv = __expf(p);
                    float qs = qadd_xor1(exv);
                    qs = qadd_xor2(qs);
                    float w = (q == 0) ? exv * __builtin_amdgcn_rcpf(qs) : 0.f;
                    _Float16 wh = (_Float16)w;
                    h2v w2; w2.x = wh; w2.y = wh;
#pragma unroll
                    for (int r = 0; r < 8; ++r) acc2[r] += w2 * t2[r];
                }
            }

            // cross-quad reduce: xor4 via ds_swizzle shfl, xor8 via DPP row_ror:8
#pragma unroll
            for (int r = 0; r < 8; ++r) {
                acc2[r] += i2h(__shfl_xor(h2i(acc2[r]), 4));
                acc2[r] += i2h(rowxor8_i(h2i(acc2[r])));
            }
            float ss = 0.f;
#pragma unroll
            for (int r = 0; r < 8; ++r) {
                vv[2*r]   = f32[2*r]   + (float)acc2[r].x;
                vv[2*r+1] = f32[2*r+1] + (float)acc2[r].y;
            }
#pragma unroll
            for (int d = 0; d < 16; ++d) ss = fmaf(vv[d], vv[d], ss);
            float inv = 1.0f / fmaxf(sqrtf(ss), 1e-12f);
#pragma unroll
            for (int d = 0; d < 16; ++d) vv[d] *= inv;
            if (pass == 0) {
#pragma unroll
                for (int r = 0; r < 8; ++r) {
                    h2v t; t.x = (_Float16)vv[2*r]; t.y = (_Float16)vv[2*r+1];
                    hh[r] = t;
                }
            }
        }

        // lane (q,k) writes dims [4q,4q+4) of factor k — static-index selects
        float4 o;
        o.x = (q==0) ? vv[0]  : (q==1) ? vv[4]  : (q==2) ? vv[8]  : vv[12];
        o.y = (q==0) ? vv[1]  : (q==1) ? vv[5]  : (q==2) ? vv[9]  : vv[13];
        o.z = (q==0) ? vv[2]  : (q==1) ? vv[6]  : (q==2) ? vv[10] : vv[14];
        o.w = (q==0) ? vv[3]  : (q==1) ? vv[7]  : (q==2) ? vv[11] : vv[15];
        ((float4*)(nf_out + (size_t)n * 64 + k * 16))[q] = o;
    }
}

// ---------------------------------------------------------------------------
extern "C" void kernel_launch(void* const* d_in, const int* in_sizes, int n_in,
                              void* d_out, int out_size, void* d_ws, size_t ws_size,
                              hipStream_t stream) {
    const float* emb = (const float*)d_in[0];
    const float* W   = (const float*)d_in[1];
    const float* b   = (const float*)d_in[2];
    const int*   row = (const int*)d_in[3];
    const int*   col = (const int*)d_in[4];

    const int N = in_sizes[0] / IN_DIM;
    const int E = in_sizes[3];

    const int NBUK   = (N + 31) >> SH;         // 32-row buckets (3125)
    const int NB_blk = (E + EPB - 1) / EPB;    // level-1 blocks (196)
    const int M      = NBUK * NB_blk;          // ~613K

    float* nf = (float*)d_out;

    // Workspace
    _Float16* fac16 = (_Float16*)d_ws;                 // N*64 halves
    int*      tmp   = (int*)(fac16 + (size_t)N * 64);  // E packed (rlow|col*128)
    int*      H     = tmp + E;                         // M (block-major)
    int*      Hscan = H + M;                           // M+1 (bucket-major)
    int*      bsum  = Hscan + (M + 1);                 // up to 1024
    int*      cnt   = bsum + 1024;                     // scan1 ticket

    const int nb1 = (M + 1023) / 1024;
    const int FB  = 512;                               // fac blocks (2048 waves)

    fac_hist_kernel<<<FB + NB_blk, 256, 0, stream>>>(
        emb, W, b, fac16, row, H, cnt, N, E, FB, NB_blk, NBUK);
    scan1_kernel<<<nb1, 1024, 0, stream>>>(H, Hscan, bsum, cnt, M, NB_blk, NBUK);
    scatter1_kernel<<<NB_blk, 256, 0, stream>>>(row, col, Hscan, bsum, tmp, E, NB_blk, NBUK);
    agg_kernel<<<NBUK, 256, 0, stream>>>(fac16, tmp, Hscan, bsum, nf, E, NB_blk, NBUK, N);
}

// Round 9
// 203.430 us; speedup vs baseline: 1.5470x; 1.1289x over previous
//
#include <hip/hip_runtime.h>

#define IN_DIM 64
#define FAC_K  4
#define DIM_K  16
#define SH     5                 // rows per bucket = 32 (sort granularity == agg block)
#define EPB    8192              // edges per level-1 histogram block
#define CAP    1536              // max edges per 32-row bucket in LDS (mean ~512, max ~600)
#define STG    256               // staged edges per bucket (32 KB LDS, pass-2 reuse)

typedef _Float16 h2v __attribute__((ext_vector_type(2)));
typedef _Float16 h8v __attribute__((ext_vector_type(8)));
typedef float    f4v __attribute__((ext_vector_type(4)));

__device__ inline int   h2i(h2v v) { return __builtin_bit_cast(int, v); }
__device__ inline h2v   i2h(int v) { return __builtin_bit_cast(h2v, v); }
__device__ inline h2v   pkh(float a, float b) {
    return __builtin_bit_cast(h2v, __builtin_amdgcn_cvt_pkrtz(a, b));
}

#if __has_builtin(__builtin_amdgcn_fdot2)
__device__ inline float FDOT2(h2v a, h2v b, float c) {
    return __builtin_amdgcn_fdot2(a, b, c, false);
}
#else
__device__ inline float FDOT2(h2v a, h2v b, float c) {
    return c + (float)a.x * (float)b.x + (float)a.y * (float)b.y;
}
#endif

// Quad (4-lane) butterfly adds via DPP quad_perm — softmax K-sum without LDS.
// Quads are uniformly active here (len/valid are quad-uniform).
__device__ inline float qadd_xor1(float x) {   // quad_perm [1,0,3,2]
    int y = __builtin_amdgcn_update_dpp(0, __builtin_bit_cast(int, x), 0xB1, 0xF, 0xF, true);
    return x + __builtin_bit_cast(float, y);
}
__device__ inline float qadd_xor2(float x) {   // quad_perm [2,3,0,1]
    int y = __builtin_amdgcn_update_dpp(0, __builtin_bit_cast(int, x), 0x4E, 0xF, 0xF, true);
    return x + __builtin_bit_cast(float, y);
}
// xor-8 within a 16-lane row == row_ror:8 (ctrl 0x128). Rows (16-lane node
// groups) are either fully active or fully skipped, so DPP reads are safe.
__device__ inline int rowxor8_i(int x) {
    return __builtin_amdgcn_update_dpp(0, x, 0x128, 0xF, 0xF, true);
}

union H8U { h8v v; h2v p[4]; };

// ---------------------------------------------------------------------------
// Fused kernel: blocks [0,FB) = MFMA fac GEMM; blocks [FB,FB+NB_blk) = hist.
// (EXACT r3 version — bucket-major flush; 5 rearrangements all regressed.)
// ---------------------------------------------------------------------------
#define TSZ 1344   // per-wave LDS floats: addr = 20*o + m + 16*(o>>4), max 1323

__global__ __launch_bounds__(256) void fac_hist_kernel(
    const float* __restrict__ emb, const float* __restrict__ W,
    const float* __restrict__ b,   _Float16* __restrict__ fac16,
    const int* __restrict__ row,   int* __restrict__ H,
    int N, int E, int FB, int NB_blk, int NBUK)
{
    __shared__ float lds_pool[4 * TSZ];   // 21.5 KB; hist aliases 12.5 KB of it
    const int tid = threadIdx.x;

    if (blockIdx.x >= FB) {
        int* hist = (int*)lds_pool;       // NBUK=3125 ints = 12.5 KB <= 21.5 KB
        const int hb   = blockIdx.x - FB;
        const int base = hb * EPB;
        for (int i = tid; i < NBUK; i += 256) hist[i] = 0;
        __syncthreads();
#pragma unroll
        for (int i = 0; i < EPB / 256; ++i) {
            int e = base + i * 256 + tid;
            if (e < E) atomicAdd(&hist[row[e] >> SH], 1);
        }
        __syncthreads();
        for (int i = tid; i < NBUK; i += 256)
            H[(size_t)i * NB_blk + hb] = hist[i];   // bucket-major
        return;
    }

    const int lane = tid & 63;
    const int l    = lane & 15;   // A: m (node-local); B: n (out col)
    const int q    = lane >> 4;   // quad
    float* T = lds_pool + (tid >> 6) * TSZ;

    // Build B-frags once per wave: Bf[t][s], out-tile t (outs 16t..16t+15),
    // k-step s (dims 32s..32s+31). Element j: W[t][32s+8q+j][l] + b[16t+l].
    H8U Bf[4][2];
#pragma unroll
    for (int t = 0; t < 4; ++t) {
        const float bv = b[16 * t + l];
#pragma unroll
        for (int s = 0; s < 2; ++s) {
            const float* wp = W + t * 1024 + (32 * s + 8 * q) * 16 + l;
#pragma unroll
            for (int jp = 0; jp < 4; ++jp) {
                float w0 = wp[(2 * jp)     * 16] + bv;
                float w1 = wp[(2 * jp + 1) * 16] + bv;
                Bf[t][s].p[jp] = pkh(w0, w1);
            }
        }
    }

    const int ntiles = (N + 15) >> 4;
    const int nw     = FB * 4;
    const int wid    = (blockIdx.x * 256 + tid) >> 6;

    for (int tile = wid; tile < ntiles; tile += nw) {
        const int n0 = tile << 4;
        int nm = n0 + l; if (nm >= N) nm = N - 1;   // clamp (stores guarded)

        f4v acc[4];
#pragma unroll
        for (int t = 0; t < 4; ++t) acc[t] = f4v{0.f, 0.f, 0.f, 0.f};

#pragma unroll
        for (int s = 0; s < 2; ++s) {
            const float4* ap = (const float4*)(emb + (size_t)nm * 64 + 32 * s + 8 * q);
            float4 a0 = ap[0], a1 = ap[1];
            H8U A;
            A.p[0] = pkh(a0.x, a0.y); A.p[1] = pkh(a0.z, a0.w);
            A.p[2] = pkh(a1.x, a1.y); A.p[3] = pkh(a1.z, a1.w);
#pragma unroll
            for (int t = 0; t < 4; ++t)
                acc[t] = __builtin_amdgcn_mfma_f32_16x16x32_f16(A.v, Bf[t][s].v, acc[t], 0, 0, 0);
        }

        // Epilogue: leaky + LDS transpose. acc[t][r] = node m=4q+r, out o=16t+l.
#pragma unroll
        for (int t = 0; t < 4; ++t) {
            f4v v = acc[t];
            f4v vr;
#pragma unroll
            for (int r = 0; r < 4; ++r)
                vr[r] = fmaxf(v[r], 0.f) + 0.2f * fminf(v[r], 0.f);
            const int o = 16 * t + l;
            ((f4v*)(T + 20 * o + 16 * t + 4 * q))[0] = vr;   // 16B-aligned
        }
        // Same-wave LDS read-back (no barrier needed): lane = (m=l, t=q).
        float vv[16];
        float ss = 0.f;
#pragma unroll
        for (int i = 0; i < 16; ++i) {
            float x = T[20 * (16 * q + i) + 16 * q + l];
            vv[i] = x;
            ss = fmaf(x, x, ss);
        }
        float inv = 1.0f / fmaxf(sqrtf(ss), 1e-12f);
        H8U o0, o1;
#pragma unroll
        for (int jp = 0; jp < 4; ++jp) {
            o0.p[jp] = pkh(vv[2 * jp]     * inv, vv[2 * jp + 1] * inv);
            o1.p[jp] = pkh(vv[8 + 2 * jp] * inv, vv[9 + 2 * jp] * inv);
        }
        if (n0 + l < N) {
            uint4* dst = (uint4*)(fac16 + (size_t)(n0 + l) * 64 + q * 16);
            dst[0] = __builtin_bit_cast(uint4, o0.v);
            dst[1] = __builtin_bit_cast(uint4, o1.v);
        }
    }
}

// ---------------------------------------------------------------------------
// Scans (EXACT r3).
// ---------------------------------------------------------------------------
__global__ __launch_bounds__(1024) void scan1_kernel(
    const int* __restrict__ in, int* __restrict__ out,
    int* __restrict__ bsum, int M)
{
    __shared__ int wsum[16];
    const int tid  = threadIdx.x;
    const int lane = tid & 63;
    const int w    = tid >> 6;
    const int gi   = blockIdx.x * 1024 + tid;

    int sc = (gi < M) ? in[gi] : 0;
#pragma unroll
    for (int d = 1; d < 64; d <<= 1) {
        int y = __shfl_up(sc, d);
        if (lane >= d) sc += y;
    }
    if (lane == 63) wsum[w] = sc;
    __syncthreads();
    if (w == 0) {
        int v = (lane < 16) ? wsum[lane] : 0;
#pragma unroll
        for (int d = 1; d < 16; d <<= 1) {
            int y = __shfl_up(v, d);
            if (lane >= d) v += y;
        }
        if (lane < 16) wsum[lane] = v;
    }
    __syncthreads();
    if (w > 0) sc += wsum[w - 1];
    if (gi < M) out[gi + 1] = sc;
    if (tid == 1023) bsum[blockIdx.x] = sc;
    if (blockIdx.x == 0 && tid == 0) out[0] = 0;
}

__global__ __launch_bounds__(1024) void scan2_kernel(int* __restrict__ bsum, int nb)
{
    __shared__ int sm[1024];
    const int tid = threadIdx.x;
    sm[tid] = (tid < nb) ? bsum[tid] : 0;
    __syncthreads();
    for (int d = 1; d < 1024; d <<= 1) {
        int t = (tid >= d) ? sm[tid - d] : 0;
        __syncthreads();
        sm[tid] += t;
        __syncthreads();
    }
    if (tid < nb) bsum[tid] = (tid > 0) ? sm[tid - 1] : 0;  // exclusive
}

// ---------------------------------------------------------------------------
// Level-1 scatter (EXACT r3). Packs (row&31)<<24 | (col<<7).
// ---------------------------------------------------------------------------
__global__ __launch_bounds__(256) void scatter1_kernel(
    const int* __restrict__ row, const int* __restrict__ col,
    const int* __restrict__ Hscan, const int* __restrict__ bsum,
    int* __restrict__ tmp, int E, int NB_blk, int NBUK)
{
    __shared__ int cur[3200];              // NBUK = 3125 cursors
    const int tid = threadIdx.x;
    const int jb  = blockIdx.x;
    const int base = jb * EPB;
    for (int i = tid; i < NBUK; i += 256) {
        int g = i * NB_blk + jb;
        int v = Hscan[g];
        if (g >= 1) v += bsum[(g - 1) >> 10];
        cur[i] = v;
    }
    __syncthreads();
#pragma unroll
    for (int it = 0; it < EPB / 256; ++it) {
        int e = base + it * 256 + tid;
        if (e < E) {
            int r = row[e];
            int pos = atomicAdd(&cur[r >> SH], 1);   // LDS atomic
            tmp[pos] = ((r & 31) << 24) | (col[e] << 7);
        }
    }
}

// ---------------------------------------------------------------------------
// Fused bucket-sort + 2-pass aggregate. r3 body + PASS-2 LDS REUSE: both
// passes gather the IDENTICAL fac16 rows (tail = original fac in both ref
// iterations). Pass 1 stages the first STG bucket-edges' rows (32 KB) in
// LDS; pass 2 serves those from LDS (rotate-swizzled k-slices, <=4-way bank
// conflict) and only the remainder through the depth-2 global pipeline.
// LDS 39.3 KB -> 4 blocks/CU; launch_bounds(256,4) also lifts the VGPR cap
// to 128 (r7's depth-4 spill cliff gone).
// ---------------------------------------------------------------------------
__global__ __launch_bounds__(256, 4) void agg_kernel(
    const _Float16* __restrict__ fac16, const int* __restrict__ tmp,
    const int* __restrict__ Hscan, const int* __restrict__ bsum,
    float* __restrict__ nf_out, int E, int NB_blk, int NBUK, int N)
{
    __shared__ int csr[CAP];
    __shared__ uint4 stage[STG * 8];   // 32 KB: edge g, k-slice (k+g)&3
    __shared__ int hist[32];
    __shared__ int curx[32];
    __shared__ int offl[33];

    const int tid = threadIdx.x;
    const int b   = blockIdx.x;         // bucket = 32 rows

    const int g0 = b * NB_blk;
    const int gE = g0 + NB_blk;
    const int start = Hscan[g0] + (g0 >= 1 ? bsum[(g0 - 1) >> 10] : 0);
    const int end   = Hscan[gE] + bsum[(gE - 1) >> 10];
    const int cnt   = end - start;
    const bool fits = (cnt <= CAP);

    if (tid < 32) hist[tid] = 0;
    __syncthreads();
    if (fits) {
        for (int i = tid; i < cnt; i += 256)
            atomicAdd(&hist[tmp[start + i] >> 24], 1);
    }
    __syncthreads();
    if (tid < 32) {
        int e = hist[tid];
        int sc = e;
#pragma unroll
        for (int d = 1; d < 32; d <<= 1) {
            int y = __shfl_up(sc, d);
            if (tid >= d) sc += y;
        }
        int ex = sc - e;
        offl[tid] = ex;
        curx[tid] = ex;
        if (tid == 31) offl[32] = sc;
    }
    __syncthreads();
    if (fits) {
        for (int i = tid; i < cnt; i += 256) {
            int u = tmp[start + i];
            int pos = atomicAdd(&curx[u >> 24], 1);
            csr[pos] = u & 0xFFFFFF;   // tail-row byte offset into fac16
        }
    }
    __syncthreads();

    const int grp = tid >> 4;         // node group 0..15
    const int k   = tid & 3;          // factor
    const int q   = (tid >> 2) & 3;   // edge slot (quad)
    const char* facB = (const char*)fac16;
    const int   kb   = k * 32;        // factor byte offset

    for (int round = 0; round < 2; ++round) {
        const int lr = round * 16 + grp;       // local row 0..31
        const int n  = (b << SH) + lr;
        if (n >= N) continue;

        const _Float16* frow = fac16 + (size_t)n * 64 + k * 16;
        uint4 fa = ((const uint4*)frow)[0];
        uint4 fb = ((const uint4*)frow)[1];
        h2v fh[8] = { i2h(fa.x), i2h(fa.y), i2h(fa.z), i2h(fa.w),
                      i2h(fb.x), i2h(fb.y), i2h(fb.z), i2h(fb.w) };
        float f32[16];
#pragma unroll
        for (int r = 0; r < 8; ++r) { f32[2*r] = (float)fh[r].x; f32[2*r+1] = (float)fh[r].y; }
        h2v hh[8];
#pragma unroll
        for (int r = 0; r < 8; ++r) hh[r] = fh[r];

        int s_l = 0, len = 0;
        if (fits) { s_l = offl[lr]; len = offl[lr + 1] - s_l; }
        // LDS-served prefix for pass 2 (all-valid, multiple of 4)
        int nl = 0;
        {
            int t = STG - s_l;
            nl = (t < 0) ? 0 : (t > len ? len : t);
            nl &= ~3;
        }

        float vv[16];
#pragma unroll 1
        for (int pass = 0; pass < 2; ++pass) {
            h2v acc2[8];
#pragma unroll
            for (int r = 0; r < 8; ++r) acc2[r] = h2v{(_Float16)0.f, (_Float16)0.f};

            if (fits) {
                if (pass == 0 && len > 0) {
                    // pass 1: depth-2 global pipeline + stage writes (g < STG)
                    int e0 = (q < len) ? q : len - 1;
                    const uint4* tp0 = (const uint4*)(facB + csr[s_l + e0] + kb);
                    uint4 ta0 = tp0[0], tb0 = tp0[1];
                    uint4 ta1 = ta0, tb1 = tb0;
                    if (len > 4) {
                        int e1 = (4 + q < len) ? 4 + q : len - 1;
                        const uint4* tp1 = (const uint4*)(facB + csr[s_l + e1] + kb);
                        ta1 = tp1[0]; tb1 = tp1[1];
                    }
                    for (int i = 0; i < len; i += 4) {
                        uint4 a = ta0, bb2 = tb0;
                        ta0 = ta1; tb0 = tb1;
                        const bool valid = (i + q) < len;
                        if (i + 8 < len) {
                            int e2 = (i + 8 + q < len) ? i + 8 + q : len - 1;
                            const uint4* tp2 = (const uint4*)(facB + csr[s_l + e2] + kb);
                            ta1 = tp2[0]; tb1 = tp2[1];
                        }
                        if (valid) {
                            int g = s_l + i + q;
                            if (g < STG) {
                                int u = (g << 3) + (((k + g) & 3) << 1);
                                stage[u] = a; stage[u + 1] = bb2;
                            }
                        }
                        h2v t2[8] = { i2h(a.x), i2h(a.y), i2h(a.z), i2h(a.w),
                                      i2h(bb2.x), i2h(bb2.y), i2h(bb2.z), i2h(bb2.w) };
                        float p = 0.f;
#pragma unroll
                        for (int r = 0; r < 8; ++r) p = FDOT2(hh[r], t2[r], p);
                        float exv = valid ? __expf(p) : 0.f;
                        float qs = qadd_xor1(exv);     // sum over K in quad (DPP)
                        qs = qadd_xor2(qs);
                        float w = valid ? exv * __builtin_amdgcn_rcpf(qs) : 0.f;
                        _Float16 wh = (_Float16)w;
                        h2v w2; w2.x = wh; w2.y = wh;
#pragma unroll
                        for (int r = 0; r < 8; ++r) acc2[r] += w2 * t2[r];   // pk_fma
                    }
                } else if (pass == 1 && len > 0) {
                    // pass 2a: LDS-served prefix (all lanes valid, no clamps)
                    for (int i = 0; i < nl; i += 4) {
                        int g = s_l + i + q;
                        int u = (g << 3) + (((k + g) & 3) << 1);
                        uint4 a = stage[u], bb2 = stage[u + 1];
                        h2v t2[8] = { i2h(a.x), i2h(a.y), i2h(a.z), i2h(a.w),
                                      i2h(bb2.x), i2h(bb2.y), i2h(bb2.z), i2h(bb2.w) };
                        float p = 0.f;
#pragma unroll
                        for (int r = 0; r < 8; ++r) p = FDOT2(hh[r], t2[r], p);
                        float exv = __expf(p);
                        float qs = qadd_xor1(exv);
                        qs = qadd_xor2(qs);
                        float w = exv * __builtin_amdgcn_rcpf(qs);
                        _Float16 wh = (_Float16)w;
                        h2v w2; w2.x = wh; w2.y = wh;
#pragma unroll
                        for (int r = 0; r < 8; ++r) acc2[r] += w2 * t2[r];
                    }
                    // pass 2b: remainder via depth-2 global pipeline
                    const int s_l2 = s_l + nl;
                    const int len2 = len - nl;
                    if (len2 > 0) {
                        int e0 = (q < len2) ? q : len2 - 1;
                        const uint4* tp0 = (const uint4*)(facB + csr[s_l2 + e0] + kb);
                        uint4 ta0 = tp0[0], tb0 = tp0[1];
                        uint4 ta1 = ta0, tb1 = tb0;
                        if (len2 > 4) {
                            int e1 = (4 + q < len2) ? 4 + q : len2 - 1;
                            const uint4* tp1 = (const uint4*)(facB + csr[s_l2 + e1] + kb);
                            ta1 = tp1[0]; tb1 = tp1[1];
                        }
                        for (int i = 0; i < len2; i += 4) {
                            uint4 a = ta0, bb2 = tb0;
                            ta0 = ta1; tb0 = tb1;
                            const bool valid = (i + q) < len2;
                            if (i + 8 < len2) {
                                int e2 = (i + 8 + q < len2) ? i + 8 + q : len2 - 1;
                                const uint4* tp2 = (const uint4*)(facB + csr[s_l2 + e2] + kb);
                                ta1 = tp2[0]; tb1 = tp2[1];
                            }
                            h2v t2[8] = { i2h(a.x), i2h(a.y), i2h(a.z), i2h(a.w),
                                          i2h(bb2.x), i2h(bb2.y), i2h(bb2.z), i2h(bb2.w) };
                            float p = 0.f;
#pragma unroll
                            for (int r = 0; r < 8; ++r) p = FDOT2(hh[r], t2[r], p);
                            float exv = valid ? __expf(p) : 0.f;
                            float qs = qadd_xor1(exv);
                            qs = qadd_xor2(qs);
                            float w = valid ? exv * __builtin_amdgcn_rcpf(qs) : 0.f;
                            _Float16 wh = (_Float16)w;
                            h2v w2; w2.x = wh; w2.y = wh;
#pragma unroll
                            for (int r = 0; r < 8; ++r) acc2[r] += w2 * t2[r];
                        }
                    }
                }
            } else {
                // Fallback (bucket overflow, never expected): filter-scan tmp.
                for (int i = 0; i < cnt; ++i) {
                    int u = tmp[start + i];
                    if ((u >> 24) != lr) continue;
                    const uint4* tp = (const uint4*)(facB + (u & 0xFFFFFF) + kb);
                    uint4 a = tp[0], bb2 = tp[1];
                    h2v t2[8] = { i2h(a.x), i2h(a.y), i2h(a.z), i2h(a.w),
                                  i2h(bb2.x), i2h(bb2.y), i2h(bb2.z), i2h(bb2.w) };
                    float p = 0.f;
#pragma unroll
                    for (int r = 0; r < 8; ++r) p = FDOT2(hh[r], t2[r], p);
                    float exv = __expf(p);
                    float qs = qadd_xor1(exv);
                    qs = qadd_xor2(qs);
                    float w = (q == 0) ? exv * __builtin_amdgcn_rcpf(qs) : 0.f;
                    _Float16 wh = (_Float16)w;
                    h2v w2; w2.x = wh; w2.y = wh;
#pragma unroll
                    for (int r = 0; r < 8; ++r) acc2[r] += w2 * t2[r];
                }
            }

            // cross-quad reduce: xor4 via ds_swizzle shfl, xor8 via DPP row_ror:8
#pragma unroll
            for (int r = 0; r < 8; ++r) {
                acc2[r] += i2h(__shfl_xor(h2i(acc2[r]), 4));
                acc2[r] += i2h(rowxor8_i(h2i(acc2[r])));
            }
            float ss = 0.f;
#pragma unroll
            for (int r = 0; r < 8; ++r) {
                vv[2*r]   = f32[2*r]   + (float)acc2[r].x;
                vv[2*r+1] = f32[2*r+1] + (float)acc2[r].y;
            }
#pragma unroll
            for (int d = 0; d < 16; ++d) ss = fmaf(vv[d], vv[d], ss);
            float inv = 1.0f / fmaxf(sqrtf(ss), 1e-12f);
#pragma unroll
            for (int d = 0; d < 16; ++d) vv[d] *= inv;
            if (pass == 0) {
#pragma unroll
                for (int r = 0; r < 8; ++r) {
                    h2v t; t.x = (_Float16)vv[2*r]; t.y = (_Float16)vv[2*r+1];
                    hh[r] = t;
                }
            }
        }

        // lane (q,k) writes dims [4q,4q+4) of factor k — static-index selects
        float4 o;
        o.x = (q==0) ? vv[0]  : (q==1) ? vv[4]  : (q==2) ? vv[8]  : vv[12];
        o.y = (q==0) ? vv[1]  : (q==1) ? vv[5]  : (q==2) ? vv[9]  : vv[13];
        o.z = (q==0) ? vv[2]  : (q==1) ? vv[6]  : (q==2) ? vv[10] : vv[14];
        o.w = (q==0) ? vv[3]  : (q==1) ? vv[7]  : (q==2) ? vv[11] : vv[15];
        ((float4*)(nf_out + (size_t)n * 64 + k * 16))[q] = o;
    }
}

// ---------------------------------------------------------------------------
extern "C" void kernel_launch(void* const* d_in, const int* in_sizes, int n_in,
                              void* d_out, int out_size, void* d_ws, size_t ws_size,
                              hipStream_t stream) {
    const float* emb = (const float*)d_in[0];
    const float* W   = (const float*)d_in[1];
    const float* b   = (const float*)d_in[2];
    const int*   row = (const int*)d_in[3];
    const int*   col = (const int*)d_in[4];

    const int N = in_sizes[0] / IN_DIM;
    const int E = in_sizes[3];

    const int NBUK   = (N + 31) >> SH;         // 32-row buckets (3125)
    const int NB_blk = (E + EPB - 1) / EPB;    // level-1 blocks (196)
    const int M      = NBUK * NB_blk;          // ~613K

    float* nf = (float*)d_out;

    // Workspace
    _Float16* fac16 = (_Float16*)d_ws;                 // N*64 halves
    int*      tmp   = (int*)(fac16 + (size_t)N * 64);  // E packed (rlow|col*128)
    int*      H     = tmp + E;                         // M
    int*      Hscan = H + M;                           // M+1
    int*      bsum  = Hscan + (M + 1);                 // up to 1024

    const int nb1 = (M + 1023) / 1024;
    const int FB  = 512;                               // fac blocks (2048 waves)

    fac_hist_kernel<<<FB + NB_blk, 256, 0, stream>>>(
        emb, W, b, fac16, row, H, N, E, FB, NB_blk, NBUK);
    scan1_kernel<<<nb1, 1024, 0, stream>>>(H, Hscan, bsum, M);
    scan2_kernel<<<1, 1024, 0, stream>>>(bsum, nb1);
    scatter1_kernel<<<NB_blk, 256, 0, stream>>>(row, col, Hscan, bsum, tmp, E, NB_blk, NBUK);
    agg_kernel<<<NBUK, 256, 0, stream>>>(fac16, tmp, Hscan, bsum, nf, E, NB_blk, NBUK, N);
}

// Round 10
// 197.358 us; speedup vs baseline: 1.5946x; 1.0308x over previous
//
#include <hip/hip_runtime.h>

#define IN_DIM 64
#define FAC_K  4
#define DIM_K  16
#define SH     5                 // rows per bucket = 32 (sort granularity == agg block)
#define EPB    8192              // edges per level-1 histogram block
#define CAP    1536              // max edges per 32-row bucket in LDS (mean ~512, max ~600)
#define STG    256               // staged edges per bucket (32 KB LDS, pass-2 reuse)

typedef _Float16 h2v __attribute__((ext_vector_type(2)));
typedef _Float16 h8v __attribute__((ext_vector_type(8)));
typedef float    f4v __attribute__((ext_vector_type(4)));

__device__ inline int   h2i(h2v v) { return __builtin_bit_cast(int, v); }
__device__ inline h2v   i2h(int v) { return __builtin_bit_cast(h2v, v); }
__device__ inline h2v   pkh(float a, float b) {
    return __builtin_bit_cast(h2v, __builtin_amdgcn_cvt_pkrtz(a, b));
}

#if __has_builtin(__builtin_amdgcn_fdot2)
__device__ inline float FDOT2(h2v a, h2v b, float c) {
    return __builtin_amdgcn_fdot2(a, b, c, false);
}
#else
__device__ inline float FDOT2(h2v a, h2v b, float c) {
    return c + (float)a.x * (float)b.x + (float)a.y * (float)b.y;
}
#endif

// Quad (4-lane) butterfly adds via DPP quad_perm — softmax K-sum without LDS.
// Quads are uniformly active here (len/valid are quad-uniform).
__device__ inline float qadd_xor1(float x) {   // quad_perm [1,0,3,2]
    int y = __builtin_amdgcn_update_dpp(0, __builtin_bit_cast(int, x), 0xB1, 0xF, 0xF, true);
    return x + __builtin_bit_cast(float, y);
}
__device__ inline float qadd_xor2(float x) {   // quad_perm [2,3,0,1]
    int y = __builtin_amdgcn_update_dpp(0, __builtin_bit_cast(int, x), 0x4E, 0xF, 0xF, true);
    return x + __builtin_bit_cast(float, y);
}
// xor-8 within a 16-lane row == row_ror:8 (ctrl 0x128). Rows (16-lane node
// groups) are either fully active or fully skipped, so DPP reads are safe.
__device__ inline int rowxor8_i(int x) {
    return __builtin_amdgcn_update_dpp(0, x, 0x128, 0xF, 0xF, true);
}

union H8U { h8v v; h2v p[4]; };

// ---------------------------------------------------------------------------
// Fused kernel: blocks [0,FB) = MFMA fac GEMM; blocks [FB,FB+NB_blk) = hist.
// (EXACT r3 version — bucket-major flush; 5 rearrangements all regressed.)
// ---------------------------------------------------------------------------
#define TSZ 1344   // per-wave LDS floats: addr = 20*o + m + 16*(o>>4), max 1323

__global__ __launch_bounds__(256) void fac_hist_kernel(
    const float* __restrict__ emb, const float* __restrict__ W,
    const float* __restrict__ b,   _Float16* __restrict__ fac16,
    const int* __restrict__ row,   int* __restrict__ H,
    int N, int E, int FB, int NB_blk, int NBUK)
{
    __shared__ float lds_pool[4 * TSZ];   // 21.5 KB; hist aliases 12.5 KB of it
    const int tid = threadIdx.x;

    if (blockIdx.x >= FB) {
        int* hist = (int*)lds_pool;       // NBUK=3125 ints = 12.5 KB <= 21.5 KB
        const int hb   = blockIdx.x - FB;
        const int base = hb * EPB;
        for (int i = tid; i < NBUK; i += 256) hist[i] = 0;
        __syncthreads();
#pragma unroll
        for (int i = 0; i < EPB / 256; ++i) {
            int e = base + i * 256 + tid;
            if (e < E) atomicAdd(&hist[row[e] >> SH], 1);
        }
        __syncthreads();
        for (int i = tid; i < NBUK; i += 256)
            H[(size_t)i * NB_blk + hb] = hist[i];   // bucket-major
        return;
    }

    const int lane = tid & 63;
    const int l    = lane & 15;   // A: m (node-local); B: n (out col)
    const int q    = lane >> 4;   // quad
    float* T = lds_pool + (tid >> 6) * TSZ;

    // Build B-frags once per wave: Bf[t][s], out-tile t (outs 16t..16t+15),
    // k-step s (dims 32s..32s+31). Element j: W[t][32s+8q+j][l] + b[16t+l].
    H8U Bf[4][2];
#pragma unroll
    for (int t = 0; t < 4; ++t) {
        const float bv = b[16 * t + l];
#pragma unroll
        for (int s = 0; s < 2; ++s) {
            const float* wp = W + t * 1024 + (32 * s + 8 * q) * 16 + l;
#pragma unroll
            for (int jp = 0; jp < 4; ++jp) {
                float w0 = wp[(2 * jp)     * 16] + bv;
                float w1 = wp[(2 * jp + 1) * 16] + bv;
                Bf[t][s].p[jp] = pkh(w0, w1);
            }
        }
    }

    const int ntiles = (N + 15) >> 4;
    const int nw     = FB * 4;
    const int wid    = (blockIdx.x * 256 + tid) >> 6;

    for (int tile = wid; tile < ntiles; tile += nw) {
        const int n0 = tile << 4;
        int nm = n0 + l; if (nm >= N) nm = N - 1;   // clamp (stores guarded)

        f4v acc[4];
#pragma unroll
        for (int t = 0; t < 4; ++t) acc[t] = f4v{0.f, 0.f, 0.f, 0.f};

#pragma unroll
        for (int s = 0; s < 2; ++s) {
            const float4* ap = (const float4*)(emb + (size_t)nm * 64 + 32 * s + 8 * q);
            float4 a0 = ap[0], a1 = ap[1];
            H8U A;
            A.p[0] = pkh(a0.x, a0.y); A.p[1] = pkh(a0.z, a0.w);
            A.p[2] = pkh(a1.x, a1.y); A.p[3] = pkh(a1.z, a1.w);
#pragma unroll
            for (int t = 0; t < 4; ++t)
                acc[t] = __builtin_amdgcn_mfma_f32_16x16x32_f16(A.v, Bf[t][s].v, acc[t], 0, 0, 0);
        }

        // Epilogue: leaky + LDS transpose. acc[t][r] = node m=4q+r, out o=16t+l.
#pragma unroll
        for (int t = 0; t < 4; ++t) {
            f4v v = acc[t];
            f4v vr;
#pragma unroll
            for (int r = 0; r < 4; ++r)
                vr[r] = fmaxf(v[r], 0.f) + 0.2f * fminf(v[r], 0.f);
            const int o = 16 * t + l;
            ((f4v*)(T + 20 * o + 16 * t + 4 * q))[0] = vr;   // 16B-aligned
        }
        // Same-wave LDS read-back (no barrier needed): lane = (m=l, t=q).
        float vv[16];
        float ss = 0.f;
#pragma unroll
        for (int i = 0; i < 16; ++i) {
            float x = T[20 * (16 * q + i) + 16 * q + l];
            vv[i] = x;
            ss = fmaf(x, x, ss);
        }
        float inv = 1.0f / fmaxf(sqrtf(ss), 1e-12f);
        H8U o0, o1;
#pragma unroll
        for (int jp = 0; jp < 4; ++jp) {
            o0.p[jp] = pkh(vv[2 * jp]     * inv, vv[2 * jp + 1] * inv);
            o1.p[jp] = pkh(vv[8 + 2 * jp] * inv, vv[9 + 2 * jp] * inv);
        }
        if (n0 + l < N) {
            uint4* dst = (uint4*)(fac16 + (size_t)(n0 + l) * 64 + q * 16);
            dst[0] = __builtin_bit_cast(uint4, o0.v);
            dst[1] = __builtin_bit_cast(uint4, o1.v);
        }
    }
}

// ---------------------------------------------------------------------------
// Scans (EXACT r3).
// ---------------------------------------------------------------------------
__global__ __launch_bounds__(1024) void scan1_kernel(
    const int* __restrict__ in, int* __restrict__ out,
    int* __restrict__ bsum, int M)
{
    __shared__ int wsum[16];
    const int tid  = threadIdx.x;
    const int lane = tid & 63;
    const int w    = tid >> 6;
    const int gi   = blockIdx.x * 1024 + tid;

    int sc = (gi < M) ? in[gi] : 0;
#pragma unroll
    for (int d = 1; d < 64; d <<= 1) {
        int y = __shfl_up(sc, d);
        if (lane >= d) sc += y;
    }
    if (lane == 63) wsum[w] = sc;
    __syncthreads();
    if (w == 0) {
        int v = (lane < 16) ? wsum[lane] : 0;
#pragma unroll
        for (int d = 1; d < 16; d <<= 1) {
            int y = __shfl_up(v, d);
            if (lane >= d) v += y;
        }
        if (lane < 16) wsum[lane] = v;
    }
    __syncthreads();
    if (w > 0) sc += wsum[w - 1];
    if (gi < M) out[gi + 1] = sc;
    if (tid == 1023) bsum[blockIdx.x] = sc;
    if (blockIdx.x == 0 && tid == 0) out[0] = 0;
}

__global__ __launch_bounds__(1024) void scan2_kernel(int* __restrict__ bsum, int nb)
{
    __shared__ int sm[1024];
    const int tid = threadIdx.x;
    sm[tid] = (tid < nb) ? bsum[tid] : 0;
    __syncthreads();
    for (int d = 1; d < 1024; d <<= 1) {
        int t = (tid >= d) ? sm[tid - d] : 0;
        __syncthreads();
        sm[tid] += t;
        __syncthreads();
    }
    if (tid < nb) bsum[tid] = (tid > 0) ? sm[tid - 1] : 0;  // exclusive
}

// ---------------------------------------------------------------------------
// Level-1 scatter (EXACT r3). Packs (row&31)<<24 | (col<<7).
// ---------------------------------------------------------------------------
__global__ __launch_bounds__(256) void scatter1_kernel(
    const int* __restrict__ row, const int* __restrict__ col,
    const int* __restrict__ Hscan, const int* __restrict__ bsum,
    int* __restrict__ tmp, int E, int NB_blk, int NBUK)
{
    __shared__ int cur[3200];              // NBUK = 3125 cursors
    const int tid = threadIdx.x;
    const int jb  = blockIdx.x;
    const int base = jb * EPB;
    for (int i = tid; i < NBUK; i += 256) {
        int g = i * NB_blk + jb;
        int v = Hscan[g];
        if (g >= 1) v += bsum[(g - 1) >> 10];
        cur[i] = v;
    }
    __syncthreads();
#pragma unroll
    for (int it = 0; it < EPB / 256; ++it) {
        int e = base + it * 256 + tid;
        if (e < E) {
            int r = row[e];
            int pos = atomicAdd(&cur[r >> SH], 1);   // LDS atomic
            tmp[pos] = ((r & 31) << 24) | (col[e] << 7);
        }
    }
}

// ---------------------------------------------------------------------------
// Fused bucket-sort + 2-pass aggregate with pass-2 LDS reuse (r9, proven:
// FETCH 181->84 MB, 71->62 us). This round: depth-4 gather pipeline in
// pass 1 / pass 2b — affordable now because launch_bounds(256,4) caps VGPR
// at 128 (r7's depth-4 spilled under the (256,8) 64-VGPR cap). 47% of
// cycles were latency-idle at 2.67 waves/SIMD; 4-deep MLP covers ~4x.
// ---------------------------------------------------------------------------
__global__ __launch_bounds__(256, 4) void agg_kernel(
    const _Float16* __restrict__ fac16, const int* __restrict__ tmp,
    const int* __restrict__ Hscan, const int* __restrict__ bsum,
    float* __restrict__ nf_out, int E, int NB_blk, int NBUK, int N)
{
    __shared__ int csr[CAP];
    __shared__ uint4 stage[STG * 8];   // 32 KB: edge g, k-slice (k+g)&3
    __shared__ int hist[32];
    __shared__ int curx[32];
    __shared__ int offl[33];

    const int tid = threadIdx.x;
    const int b   = blockIdx.x;         // bucket = 32 rows

    const int g0 = b * NB_blk;
    const int gE = g0 + NB_blk;
    const int start = Hscan[g0] + (g0 >= 1 ? bsum[(g0 - 1) >> 10] : 0);
    const int end   = Hscan[gE] + bsum[(gE - 1) >> 10];
    const int cnt   = end - start;
    const bool fits = (cnt <= CAP);

    if (tid < 32) hist[tid] = 0;
    __syncthreads();
    if (fits) {
        for (int i = tid; i < cnt; i += 256)
            atomicAdd(&hist[tmp[start + i] >> 24], 1);
    }
    __syncthreads();
    if (tid < 32) {
        int e = hist[tid];
        int sc = e;
#pragma unroll
        for (int d = 1; d < 32; d <<= 1) {
            int y = __shfl_up(sc, d);
            if (tid >= d) sc += y;
        }
        int ex = sc - e;
        offl[tid] = ex;
        curx[tid] = ex;
        if (tid == 31) offl[32] = sc;
    }
    __syncthreads();
    if (fits) {
        for (int i = tid; i < cnt; i += 256) {
            int u = tmp[start + i];
            int pos = atomicAdd(&curx[u >> 24], 1);
            csr[pos] = u & 0xFFFFFF;   // tail-row byte offset into fac16
        }
    }
    __syncthreads();

    const int grp = tid >> 4;         // node group 0..15
    const int k   = tid & 3;          // factor
    const int q   = (tid >> 2) & 3;   // edge slot (quad)
    const char* facB = (const char*)fac16;
    const int   kb   = k * 32;        // factor byte offset

    for (int round = 0; round < 2; ++round) {
        const int lr = round * 16 + grp;       // local row 0..31
        const int n  = (b << SH) + lr;
        if (n >= N) continue;

        const _Float16* frow = fac16 + (size_t)n * 64 + k * 16;
        uint4 fa = ((const uint4*)frow)[0];
        uint4 fb = ((const uint4*)frow)[1];
        h2v fh[8] = { i2h(fa.x), i2h(fa.y), i2h(fa.z), i2h(fa.w),
                      i2h(fb.x), i2h(fb.y), i2h(fb.z), i2h(fb.w) };
        float f32[16];
#pragma unroll
        for (int r = 0; r < 8; ++r) { f32[2*r] = (float)fh[r].x; f32[2*r+1] = (float)fh[r].y; }
        h2v hh[8];
#pragma unroll
        for (int r = 0; r < 8; ++r) hh[r] = fh[r];

        int s_l = 0, len = 0;
        if (fits) { s_l = offl[lr]; len = offl[lr + 1] - s_l; }
        // LDS-served prefix for pass 2 (all-valid, multiple of 4)
        int nl = 0;
        {
            int t = STG - s_l;
            nl = (t < 0) ? 0 : (t > len ? len : t);
            nl &= ~3;
        }

        float vv[16];
#pragma unroll 1
        for (int pass = 0; pass < 2; ++pass) {
            h2v acc2[8];
#pragma unroll
            for (int r = 0; r < 8; ++r) acc2[r] = h2v{(_Float16)0.f, (_Float16)0.f};

            if (fits) {
                if (pass == 0 && len > 0) {
                    // pass 1: depth-4 global pipeline + stage writes (g < STG)
                    int e0 = (q < len)      ? q      : len - 1;
                    int e1 = (4 + q < len)  ? 4 + q  : len - 1;
                    int e2 = (8 + q < len)  ? 8 + q  : len - 1;
                    int e3 = (12 + q < len) ? 12 + q : len - 1;
                    const uint4* tp0 = (const uint4*)(facB + csr[s_l + e0] + kb);
                    const uint4* tp1 = (const uint4*)(facB + csr[s_l + e1] + kb);
                    const uint4* tp2 = (const uint4*)(facB + csr[s_l + e2] + kb);
                    const uint4* tp3 = (const uint4*)(facB + csr[s_l + e3] + kb);
                    uint4 ta0 = tp0[0], tb0 = tp0[1];
                    uint4 ta1 = tp1[0], tb1 = tp1[1];
                    uint4 ta2 = tp2[0], tb2 = tp2[1];
                    uint4 ta3 = tp3[0], tb3 = tp3[1];
                    for (int i = 0; i < len; i += 4) {
                        uint4 a = ta0, bb2 = tb0;
                        ta0 = ta1; tb0 = tb1;
                        ta1 = ta2; tb1 = tb2;
                        ta2 = ta3; tb2 = tb3;
                        const bool valid = (i + q) < len;
                        if (i + 16 < len) {
                            int en = (i + 16 + q < len) ? i + 16 + q : len - 1;
                            const uint4* tpn = (const uint4*)(facB + csr[s_l + en] + kb);
                            ta3 = tpn[0]; tb3 = tpn[1];
                        }
                        if (valid) {
                            int g = s_l + i + q;
                            if (g < STG) {
                                int u = (g << 3) + (((k + g) & 3) << 1);
                                stage[u] = a; stage[u + 1] = bb2;
                            }
                        }
                        h2v t2[8] = { i2h(a.x), i2h(a.y), i2h(a.z), i2h(a.w),
                                      i2h(bb2.x), i2h(bb2.y), i2h(bb2.z), i2h(bb2.w) };
                        float p = 0.f;
#pragma unroll
                        for (int r = 0; r < 8; ++r) p = FDOT2(hh[r], t2[r], p);
                        float exv = valid ? __expf(p) : 0.f;
                        float qs = qadd_xor1(exv);     // sum over K in quad (DPP)
                        qs = qadd_xor2(qs);
                        float w = valid ? exv * __builtin_amdgcn_rcpf(qs) : 0.f;
                        _Float16 wh = (_Float16)w;
                        h2v w2; w2.x = wh; w2.y = wh;
#pragma unroll
                        for (int r = 0; r < 8; ++r) acc2[r] += w2 * t2[r];   // pk_fma
                    }
                } else if (pass == 1 && len > 0) {
                    // pass 2a: LDS-served prefix (all lanes valid, no clamps)
                    for (int i = 0; i < nl; i += 4) {
                        int g = s_l + i + q;
                        int u = (g << 3) + (((k + g) & 3) << 1);
                        uint4 a = stage[u], bb2 = stage[u + 1];
                        h2v t2[8] = { i2h(a.x), i2h(a.y), i2h(a.z), i2h(a.w),
                                      i2h(bb2.x), i2h(bb2.y), i2h(bb2.z), i2h(bb2.w) };
                        float p = 0.f;
#pragma unroll
                        for (int r = 0; r < 8; ++r) p = FDOT2(hh[r], t2[r], p);
                        float exv = __expf(p);
                        float qs = qadd_xor1(exv);
                        qs = qadd_xor2(qs);
                        float w = exv * __builtin_amdgcn_rcpf(qs);
                        _Float16 wh = (_Float16)w;
                        h2v w2; w2.x = wh; w2.y = wh;
#pragma unroll
                        for (int r = 0; r < 8; ++r) acc2[r] += w2 * t2[r];
                    }
                    // pass 2b: remainder via depth-4 global pipeline
                    const int s_l2 = s_l + nl;
                    const int len2 = len - nl;
                    if (len2 > 0) {
                        int e0 = (q < len2)      ? q      : len2 - 1;
                        int e1 = (4 + q < len2)  ? 4 + q  : len2 - 1;
                        int e2 = (8 + q < len2)  ? 8 + q  : len2 - 1;
                        int e3 = (12 + q < len2) ? 12 + q : len2 - 1;
                        const uint4* tp0 = (const uint4*)(facB + csr[s_l2 + e0] + kb);
                        const uint4* tp1 = (const uint4*)(facB + csr[s_l2 + e1] + kb);
                        const uint4* tp2 = (const uint4*)(facB + csr[s_l2 + e2] + kb);
                        const uint4* tp3 = (const uint4*)(facB + csr[s_l2 + e3] + kb);
                        uint4 ta0 = tp0[0], tb0 = tp0[1];
                        uint4 ta1 = tp1[0], tb1 = tp1[1];
                        uint4 ta2 = tp2[0], tb2 = tp2[1];
                        uint4 ta3 = tp3[0], tb3 = tp3[1];
                        for (int i = 0; i < len2; i += 4) {
                            uint4 a = ta0, bb2 = tb0;
                            ta0 = ta1; tb0 = tb1;
                            ta1 = ta2; tb1 = tb2;
                            ta2 = ta3; tb2 = tb3;
                            const bool valid = (i + q) < len2;
                            if (i + 16 < len2) {
                                int en = (i + 16 + q < len2) ? i + 16 + q : len2 - 1;
                                const uint4* tpn = (const uint4*)(facB + csr[s_l2 + en] + kb);
                                ta3 = tpn[0]; tb3 = tpn[1];
                            }
                            h2v t2[8] = { i2h(a.x), i2h(a.y), i2h(a.z), i2h(a.w),
                                          i2h(bb2.x), i2h(bb2.y), i2h(bb2.z), i2h(bb2.w) };
                            float p = 0.f;
#pragma unroll
                            for (int r = 0; r < 8; ++r) p = FDOT2(hh[r], t2[r], p);
                            float exv = valid ? __expf(p) : 0.f;
                            float qs = qadd_xor1(exv);
                            qs = qadd_xor2(qs);
                            float w = valid ? exv * __builtin_amdgcn_rcpf(qs) : 0.f;
                            _Float16 wh = (_Float16)w;
                            h2v w2; w2.x = wh; w2.y = wh;
#pragma unroll
                            for (int r = 0; r < 8; ++r) acc2[r] += w2 * t2[r];
                        }
                    }
                }
            } else {
                // Fallback (bucket overflow, never expected): filter-scan tmp.
                for (int i = 0; i < cnt; ++i) {
                    int u = tmp[start + i];
                    if ((u >> 24) != lr) continue;
                    const uint4* tp = (const uint4*)(facB + (u & 0xFFFFFF) + kb);
                    uint4 a = tp[0], bb2 = tp[1];
                    h2v t2[8] = { i2h(a.x), i2h(a.y), i2h(a.z), i2h(a.w),
                                  i2h(bb2.x), i2h(bb2.y), i2h(bb2.z), i2h(bb2.w) };
                    float p = 0.f;
#pragma unroll
                    for (int r = 0; r < 8; ++r) p = FDOT2(hh[r], t2[r], p);
                    float exv = __expf(p);
                    float qs = qadd_xor1(exv);
                    qs = qadd_xor2(qs);
                    float w = (q == 0) ? exv * __builtin_amdgcn_rcpf(qs) : 0.f;
                    _Float16 wh = (_Float16)w;
                    h2v w2; w2.x = wh; w2.y = wh;
#pragma unroll
                    for (int r = 0; r < 8; ++r) acc2[r] += w2 * t2[r];
                }
            }

            // cross-quad reduce: xor4 via ds_swizzle shfl, xor8 via DPP row_ror:8
#pragma unroll
            for (int r = 0; r < 8; ++r) {
                acc2[r] += i2h(__shfl_xor(h2i(acc2[r]), 4));
                acc2[r] += i2h(rowxor8_i(h2i(acc2[r])));
            }
            float ss = 0.f;
#pragma unroll
            for (int r = 0; r < 8; ++r) {
                vv[2*r]   = f32[2*r]   + (float)acc2[r].x;
                vv[2*r+1] = f32[2*r+1] + (float)acc2[r].y;
            }
#pragma unroll
            for (int d = 0; d < 16; ++d) ss = fmaf(vv[d], vv[d], ss);
            float inv = 1.0f / fmaxf(sqrtf(ss), 1e-12f);
#pragma unroll
            for (int d = 0; d < 16; ++d) vv[d] *= inv;
            if (pass == 0) {
#pragma unroll
                for (int r = 0; r < 8; ++r) {
                    h2v t; t.x = (_Float16)vv[2*r]; t.y = (_Float16)vv[2*r+1];
                    hh[r] = t;
                }
            }
        }

        // lane (q,k) writes dims [4q,4q+4) of factor k — static-index selects
        float4 o;
        o.x = (q==0) ? vv[0]  : (q==1) ? vv[4]  : (q==2) ? vv[8]  : vv[12];
        o.y = (q==0) ? vv[1]  : (q==1) ? vv[5]  : (q==2) ? vv[9]  : vv[13];
        o.z = (q==0) ? vv[2]  : (q==1) ? vv[6]  : (q==2) ? vv[10] : vv[14];
        o.w = (q==0) ? vv[3]  : (q==1) ? vv[7]  : (q==2) ? vv[11] : vv[15];
        ((float4*)(nf_out + (size_t)n * 64 + k * 16))[q] = o;
    }
}

// ---------------------------------------------------------------------------
extern "C" void kernel_launch(void* const* d_in, const int* in_sizes, int n_in,
                              void* d_out, int out_size, void* d_ws, size_t ws_size,
                              hipStream_t stream) {
    const float* emb = (const float*)d_in[0];
    const float* W   = (const float*)d_in[1];
    const float* b   = (const float*)d_in[2];
    const int*   row = (const int*)d_in[3];
    const int*   col = (const int*)d_in[4];

    const int N = in_sizes[0] / IN_DIM;
    const int E = in_sizes[3];

    const int NBUK   = (N + 31) >> SH;         // 32-row buckets (3125)
    const int NB_blk = (E + EPB - 1) / EPB;    // level-1 blocks (196)
    const int M      = NBUK * NB_blk;          // ~613K

    float* nf = (float*)d_out;

    // Workspace
    _Float16* fac16 = (_Float16*)d_ws;                 // N*64 halves
    int*      tmp   = (int*)(fac16 + (size_t)N * 64);  // E packed (rlow|col*128)
    int*      H     = tmp + E;                         // M
    int*      Hscan = H + M;                           // M+1
    int*      bsum  = Hscan + (M + 1);                 // up to 1024

    const int nb1 = (M + 1023) / 1024;
    const int FB  = 512;                               // fac blocks (2048 waves)

    fac_hist_kernel<<<FB + NB_blk, 256, 0, stream>>>(
        emb, W, b, fac16, row, H, N, E, FB, NB_blk, NBUK);
    scan1_kernel<<<nb1, 1024, 0, stream>>>(H, Hscan, bsum, M);
    scan2_kernel<<<1, 1024, 0, stream>>>(bsum, nb1);
    scatter1_kernel<<<NB_blk, 256, 0, stream>>>(row, col, Hscan, bsum, tmp, E, NB_blk, NBUK);
    agg_kernel<<<NBUK, 256, 0, stream>>>(fac16, tmp, Hscan, bsum, nf, E, NB_blk, NBUK, N);
}